// Round 4
// baseline (738.897 us; speedup 1.0000x reference)
//
#include <hip/hip_runtime.h>
#include <math.h>

// ---- problem constants (fixed by reference) ----
#define B_SZ 512
#define D_SZ 256
#define C_SZ 100000
#define S_SCALE 30.0f
#define COS_Mc 0.8775825618903728f        // cos(0.5)
#define SIN_Mc 0.479425538604203f         // sin(0.5)
#define THRESHOLDc (-0.8775825618903728f) // cos(pi-0.5)
#define MMc 0.2397127693021015f           // sin(pi-0.5)*0.5
#define EPSc 1e-12f

// d_out layout (floats): [logits B*C][new_weight C*D][t_new 1]
#define OUT_W_OFF ((size_t)B_SZ * C_SZ)             // 51,200,000
#define OUT_T_OFF (OUT_W_OFF + (size_t)C_SZ * D_SZ) // 76,800,000

// ws layout (bytes)
#define WSB_F 0              // f fp32 [512][256]        (524288 B)
#define WSB_FHI 524288       // f_hi bf16 [512][256]     (262144 B)
#define WSB_FLO 786432       // f_lo bf16 [512][256]     (262144 B)
#define WSB_TL 1048576       // target_logit [512] f32
#define WSB_CTM 1050624      // cos_theta_m [512] f32
#define WSB_FLT 1052672      // final_target_logit [512] f32
#define WSB_TNEW 1054720     // t_new [1] f32

typedef __attribute__((ext_vector_type(8))) short bf16x8; // MFMA A/B frag (4 VGPRs)
typedef __attribute__((ext_vector_type(4))) float f32x4;  // MFMA C/D frag

__device__ __forceinline__ float wave_reduce_sum(float v) {
#pragma unroll
    for (int off = 32; off > 0; off >>= 1) v += __shfl_down(v, off, 64);
    return v;
}

__device__ __forceinline__ unsigned short f2bf(float x) { // RNE fp32->bf16
    union { float f; unsigned u; } v; v.f = x;
    unsigned r = v.u + 0x7fff + ((v.u >> 16) & 1);
    return (unsigned short)(r >> 16);
}
__device__ __forceinline__ float bf2f(unsigned short h) {
    union { float f; unsigned u; } v;
    v.u = ((unsigned)h) << 16;
    return v.f;
}

// One block per batch row: normalize, emit f / f_hi / f_lo, target dot, margin scalars.
__global__ __launch_bounds__(256) void prep_kernel(
    const float* __restrict__ features, const int* __restrict__ targets,
    const float* __restrict__ weight, float* __restrict__ f,
    unsigned short* __restrict__ fhi, unsigned short* __restrict__ flo,
    float* __restrict__ tl, float* __restrict__ ctm, float* __restrict__ flt) {
    int b = blockIdx.x;
    int d = threadIdx.x;
    float x = features[b * D_SZ + d];
    float v = wave_reduce_sum(x * x);
    __shared__ float red[4];
    int wave = d >> 6, lane = d & 63;
    if (lane == 0) red[wave] = v;
    __syncthreads();
    float s = red[0] + red[1] + red[2] + red[3];
    float scale = 1.0f / fmaxf(sqrtf(s), EPSc);
    float fv = x * scale;
    f[b * D_SZ + d] = fv;
    unsigned short h = f2bf(fv);
    fhi[b * D_SZ + d] = h;
    flo[b * D_SZ + d] = f2bf(fv - bf2f(h));

    int tgt = targets[b];
    float wv = weight[(size_t)tgt * D_SZ + d];
    float p = wave_reduce_sum(fv * wv);
    __syncthreads();
    if (lane == 0) red[wave] = p;
    __syncthreads();
    if (d == 0) {
        float t_l = red[0] + red[1] + red[2] + red[3];
        tl[b] = t_l;
        float sin_t = sqrtf(fmaxf(1.0f - t_l * t_l, 0.0f));
        float c_m = t_l * COS_Mc - sin_t * SIN_Mc;
        ctm[b] = c_m;
        flt[b] = (t_l > THRESHOLDc) ? c_m : (t_l - MMc);
    }
}

// One block: t_new = mean(tl)*0.01 + 0.99*t
__global__ __launch_bounds__(512) void tnew_kernel(
    const float* __restrict__ tl, const float* __restrict__ t_in,
    float* __restrict__ tnew_ws, float* __restrict__ out_t) {
    int i = threadIdx.x;
    float v = wave_reduce_sum(tl[i]);
    __shared__ float red[8];
    int wave = i >> 6, lane = i & 63;
    if (lane == 0) red[wave] = v;
    __syncthreads();
    if (i == 0) {
        float s = 0.f;
#pragma unroll
        for (int w = 0; w < 8; w++) s += red[w];
        float tn = (s / (float)B_SZ) * 0.01f + 0.99f * t_in[0];
        tnew_ws[0] = tn;
        out_t[0] = tn;
    }
}

// One-time W split: fp32 [C][D] -> Whi, Wlo bf16 row-major (each C*D ushorts).
// 8 floats per thread; C*D = 25,600,000 = 12500 blocks * 256 thr * 8.
__global__ __launch_bounds__(256) void wpack_kernel(
    const float* __restrict__ w, unsigned short* __restrict__ whi,
    unsigned short* __restrict__ wlo) {
    size_t i = ((size_t)blockIdx.x * 256 + threadIdx.x) * 8;
    float4 a = *(const float4*)&w[i];
    float4 b = *(const float4*)&w[i + 4];
    union { unsigned short us[8]; bf16x8 v; } h, l;
    float xs[8] = {a.x, a.y, a.z, a.w, b.x, b.y, b.z, b.w};
#pragma unroll
    for (int j = 0; j < 8; j++) {
        unsigned short hh = f2bf(xs[j]);
        h.us[j] = hh;
        l.us[j] = f2bf(xs[j] - bf2f(hh));
    }
    *(bf16x8*)&whi[i] = h.v;
    *(bf16x8*)&wlo[i] = l.v;
}

// LDS-free split-bf16 MFMA GEMM with fused ArcFace epilogue.
// Block = 256 thr = 4 waves stacked in M; block tile 256 rows x 64 cols.
// Wave tile 64x64 = 4x4 frags of mfma_f32_16x16x32_bf16. No __syncthreads.
__global__ __launch_bounds__(256) void gemm_kernel(
    const unsigned short* __restrict__ fhi, const unsigned short* __restrict__ flo,
    const unsigned short* __restrict__ whi, const unsigned short* __restrict__ wlo,
    const int* __restrict__ targets, const float* __restrict__ ctm,
    const float* __restrict__ flt, const float* __restrict__ tnew,
    float* __restrict__ out) {
    const int t = threadIdx.x;
    const int w = t >> 6, lane = t & 63;
    const int fr = lane & 15;       // frag row (A) / col (B,D)
    const int kg = (lane >> 4) * 8; // frag k-offset (elements)
    const int col0 = blockIdx.x * 64;
    const int row0 = blockIdx.y * 256 + w * 64;

    bool nval[4];
#pragma unroll
    for (int ni = 0; ni < 4; ni++) nval[ni] = (col0 + ni * 16) < C_SZ; // C%16==0

    const unsigned short* arow[4];
    const unsigned short* brow[4];
#pragma unroll
    for (int mi = 0; mi < 4; mi++)
        arow[mi] = fhi + (size_t)(row0 + mi * 16 + fr) * D_SZ + kg;
#pragma unroll
    for (int ni = 0; ni < 4; ni++)
        brow[ni] = whi + (size_t)(col0 + ni * 16 + fr) * D_SZ + kg;
    const size_t dlo_f = (size_t)(flo - fhi); // const element offset
    const size_t dlo_w = (size_t)(wlo - whi);

    f32x4 acc[4][4] = {};

#pragma unroll 2
    for (int kt = 0; kt < D_SZ; kt += 32) {
        bf16x8 ah[4], al[4], bh[4], bl[4];
#pragma unroll
        for (int mi = 0; mi < 4; mi++) {
            ah[mi] = *(const bf16x8*)(arow[mi] + kt);
            al[mi] = *(const bf16x8*)(arow[mi] + kt + dlo_f);
        }
#pragma unroll
        for (int ni = 0; ni < 4; ni++) {
            if (nval[ni]) {
                bh[ni] = *(const bf16x8*)(brow[ni] + kt);
                bl[ni] = *(const bf16x8*)(brow[ni] + kt + dlo_w);
            } else {
                bh[ni] = (bf16x8)0;
                bl[ni] = (bf16x8)0;
            }
        }
#pragma unroll
        for (int mi = 0; mi < 4; mi++)
#pragma unroll
            for (int ni = 0; ni < 4; ni++) {
                acc[mi][ni] = __builtin_amdgcn_mfma_f32_16x16x32_bf16(
                    ah[mi], bh[ni], acc[mi][ni], 0, 0, 0);
                acc[mi][ni] = __builtin_amdgcn_mfma_f32_16x16x32_bf16(
                    ah[mi], bl[ni], acc[mi][ni], 0, 0, 0);
                acc[mi][ni] = __builtin_amdgcn_mfma_f32_16x16x32_bf16(
                    al[mi], bh[ni], acc[mi][ni], 0, 0, 0);
            }
    }

    // fused ArcFace epilogue; D frag: col = lane&15, row = (lane>>4)*4 + reg
    float tn = tnew[0];
#pragma unroll
    for (int mi = 0; mi < 4; mi++) {
#pragma unroll
        for (int j = 0; j < 4; j++) {
            int r = row0 + mi * 16 + (lane >> 4) * 4 + j;
            int tg = targets[r];
            float cm = ctm[r], fl = flt[r];
            size_t base = (size_t)r * C_SZ;
#pragma unroll
            for (int ni = 0; ni < 4; ni++) {
                if (nval[ni]) {
                    int c = col0 + ni * 16 + fr;
                    float v = acc[mi][ni][j];
                    if (c == tg) v = fl;
                    else if (v > cm) v = v * (tn + v);
                    out[base + c] = v * S_SCALE;
                }
            }
        }
    }
}

// bulk copy weight -> out new_weight region (overwrites packed Whi/Wlo AFTER gemm)
__global__ __launch_bounds__(256) void copyw_kernel(
    const float4* __restrict__ src, float4* __restrict__ dst, int n4) {
    int i = blockIdx.x * blockDim.x + threadIdx.x;
    if (i < n4) dst[i] = src[i];
}

// per-unique-target EMA weight update; targets cached in LDS, parallel dedup.
__global__ __launch_bounds__(256) void updw_kernel(
    const int* __restrict__ targets, const float* __restrict__ f,
    const float* __restrict__ weight, float* __restrict__ outw) {
    __shared__ int tg[B_SZ];
    __shared__ int dup;
    int t = threadIdx.x;
    if (t == 0) dup = 0;
    tg[t] = targets[t];
    tg[t + 256] = targets[t + 256];
    __syncthreads();
    int b = blockIdx.x;
    int c = tg[b];
    if ((t < b && tg[t] == c) || (t + 256 < b && tg[t + 256] == c)) dup = 1;
    __syncthreads();
    if (dup) return; // uniform: not the first occurrence

    float sum = 0.f;
    int cnt = 0;
    for (int i = b; i < B_SZ; i++) {
        if (tg[i] == c) { sum += f[i * D_SZ + t]; cnt++; }
    }
    float mean = sum / (float)cnt;
    float upd = 0.5f * weight[(size_t)c * D_SZ + t] + 0.5f * mean;
    float v = wave_reduce_sum(upd * upd);
    __shared__ float red[4];
    int wave = t >> 6, lane = t & 63;
    if (lane == 0) red[wave] = v;
    __syncthreads();
    float s = red[0] + red[1] + red[2] + red[3];
    float nrm = fmaxf(sqrtf(s), EPSc);
    outw[(size_t)c * D_SZ + t] = upd / nrm;
}

extern "C" void kernel_launch(void* const* d_in, const int* in_sizes, int n_in,
                              void* d_out, int out_size, void* d_ws, size_t ws_size,
                              hipStream_t stream) {
    const float* features = (const float*)d_in[0];
    const int* targets = (const int*)d_in[1];
    const float* weight = (const float*)d_in[2];
    const float* t_in = (const float*)d_in[3];
    float* out = (float*)d_out;
    char* wsb = (char*)d_ws;

    float* f = (float*)(wsb + WSB_F);
    unsigned short* fhi = (unsigned short*)(wsb + WSB_FHI);
    unsigned short* flo = (unsigned short*)(wsb + WSB_FLO);
    float* tl = (float*)(wsb + WSB_TL);
    float* ctm = (float*)(wsb + WSB_CTM);
    float* flt = (float*)(wsb + WSB_FLT);
    float* tnew = (float*)(wsb + WSB_TNEW);

    // packed split-W lives in the out new_weight region until copyw/updw
    unsigned short* whi = (unsigned short*)(out + OUT_W_OFF);
    unsigned short* wlo = whi + (size_t)C_SZ * D_SZ;

    prep_kernel<<<B_SZ, 256, 0, stream>>>(features, targets, weight, f, fhi, flo,
                                          tl, ctm, flt);
    tnew_kernel<<<1, 512, 0, stream>>>(tl, t_in, tnew, out + OUT_T_OFF);

    wpack_kernel<<<12500, 256, 0, stream>>>(weight, whi, wlo);

    dim3 ggrid((C_SZ + 63) / 64, 2); // 1563 x 2 blocks, 256 thr (4 waves in M)
    gemm_kernel<<<ggrid, 256, 0, stream>>>(fhi, flo, whi, wlo, targets, ctm, flt,
                                           tnew, out);

    int n4 = (C_SZ * D_SZ) / 4;
    copyw_kernel<<<(n4 + 255) / 256, 256, 0, stream>>>(
        (const float4*)weight, (float4*)(out + OUT_W_OFF), n4);

    updw_kernel<<<B_SZ, 256, 0, stream>>>(targets, f, weight, out + OUT_W_OFF);
}

// Round 5
// 582.188 us; speedup vs baseline: 1.2692x; 1.2692x over previous
//
#include <hip/hip_runtime.h>
#include <math.h>

// ---- problem constants (fixed by reference) ----
#define B_SZ 512
#define D_SZ 256
#define C_SZ 100000
#define S_SCALE 30.0f
#define COS_Mc 0.8775825618903728f        // cos(0.5)
#define SIN_Mc 0.479425538604203f         // sin(0.5)
#define THRESHOLDc (-0.8775825618903728f) // cos(pi-0.5)
#define MMc 0.2397127693021015f           // sin(pi-0.5)*0.5
#define EPSc 1e-12f

// d_out layout (floats): [logits B*C][new_weight C*D][t_new 1]
#define OUT_W_OFF ((size_t)B_SZ * C_SZ)             // 51,200,000
#define OUT_T_OFF (OUT_W_OFF + (size_t)C_SZ * D_SZ) // 76,800,000

// ws layout (bytes)
#define WSB_F 0              // f fp32 [512][256]
#define WSB_FHI 524288       // f_hi bf16 [512][256]
#define WSB_FLO 786432       // f_lo bf16 [512][256]
#define WSB_TL 1048576       // target_logit [512] f32
#define WSB_CTM 1050624      // cos_theta_m [512] f32
#define WSB_FLT 1052672      // final_target_logit [512] f32
#define WSB_TNEW 1054720     // t_new [1] f32

typedef __attribute__((ext_vector_type(8))) short bf16x8; // MFMA A/B frag
typedef __attribute__((ext_vector_type(4))) float f32x4;  // MFMA C/D frag
typedef __attribute__((address_space(3))) void lds_void;
typedef const __attribute__((address_space(1))) void g_void;

__device__ __forceinline__ float wave_reduce_sum(float v) {
#pragma unroll
    for (int off = 32; off > 0; off >>= 1) v += __shfl_down(v, off, 64);
    return v;
}

__device__ __forceinline__ unsigned short f2bf(float x) { // RNE fp32->bf16
    union { float f; unsigned u; } v; v.f = x;
    unsigned r = v.u + 0x7fff + ((v.u >> 16) & 1);
    return (unsigned short)(r >> 16);
}
__device__ __forceinline__ float bf2f(unsigned short h) {
    union { float f; unsigned u; } v;
    v.u = ((unsigned)h) << 16;
    return v.f;
}

// One block per batch row: normalize, emit f / f_hi / f_lo, target dot, margin scalars.
__global__ __launch_bounds__(256) void prep_kernel(
    const float* __restrict__ features, const int* __restrict__ targets,
    const float* __restrict__ weight, float* __restrict__ f,
    unsigned short* __restrict__ fhi, unsigned short* __restrict__ flo,
    float* __restrict__ tl, float* __restrict__ ctm, float* __restrict__ flt) {
    int b = blockIdx.x;
    int d = threadIdx.x;
    float x = features[b * D_SZ + d];
    float v = wave_reduce_sum(x * x);
    __shared__ float red[4];
    int wave = d >> 6, lane = d & 63;
    if (lane == 0) red[wave] = v;
    __syncthreads();
    float s = red[0] + red[1] + red[2] + red[3];
    float scale = 1.0f / fmaxf(sqrtf(s), EPSc);
    float fv = x * scale;
    f[b * D_SZ + d] = fv;
    unsigned short h = f2bf(fv);
    fhi[b * D_SZ + d] = h;
    flo[b * D_SZ + d] = f2bf(fv - bf2f(h));

    int tgt = targets[b];
    float wv = weight[(size_t)tgt * D_SZ + d];
    float p = wave_reduce_sum(fv * wv);
    __syncthreads();
    if (lane == 0) red[wave] = p;
    __syncthreads();
    if (d == 0) {
        float t_l = red[0] + red[1] + red[2] + red[3];
        tl[b] = t_l;
        float sin_t = sqrtf(fmaxf(1.0f - t_l * t_l, 0.0f));
        float c_m = t_l * COS_Mc - sin_t * SIN_Mc;
        ctm[b] = c_m;
        flt[b] = (t_l > THRESHOLDc) ? c_m : (t_l - MMc);
    }
}

// One block: t_new = mean(tl)*0.01 + 0.99*t
__global__ __launch_bounds__(512) void tnew_kernel(
    const float* __restrict__ tl, const float* __restrict__ t_in,
    float* __restrict__ tnew_ws, float* __restrict__ out_t) {
    int i = threadIdx.x;
    float v = wave_reduce_sum(tl[i]);
    __shared__ float red[8];
    int wave = i >> 6, lane = i & 63;
    if (lane == 0) red[wave] = v;
    __syncthreads();
    if (i == 0) {
        float s = 0.f;
#pragma unroll
        for (int w = 0; w < 8; w++) s += red[w];
        float tn = (s / (float)B_SZ) * 0.01f + 0.99f * t_in[0];
        tnew_ws[0] = tn;
        out_t[0] = tn;
    }
}

// One-time W split: fp32 [C][D] -> Whi, Wlo bf16 row-major.
__global__ __launch_bounds__(256) void wpack_kernel(
    const float* __restrict__ w, unsigned short* __restrict__ whi,
    unsigned short* __restrict__ wlo) {
    size_t i = ((size_t)blockIdx.x * 256 + threadIdx.x) * 8;
    float4 a = *(const float4*)&w[i];
    float4 b = *(const float4*)&w[i + 4];
    union { unsigned short us[8]; bf16x8 v; } h, l;
    float xs[8] = {a.x, a.y, a.z, a.w, b.x, b.y, b.z, b.w};
#pragma unroll
    for (int j = 0; j < 8; j++) {
        unsigned short hh = f2bf(xs[j]);
        h.us[j] = hh;
        l.us[j] = f2bf(xs[j] - bf2f(hh));
    }
    *(bf16x8*)&whi[i] = h.v;
    *(bf16x8*)&wlo[i] = l.v;
}

// m97-style LDS-staged split-bf16 MFMA GEMM with fused ArcFace epilogue.
// Block 128x128, BK=32, 4 waves 2x2 (wave tile 64x64 = 4x4 frags 16x16x32).
// global_load_lds(16B) staging with XOR-swizzled LDS layout:
//   phys_byte(r, o) = r*64 + (o ^ (((r>>1)&3)<<4))   [o = byte-in-row 0..63]
// -> uniform 2-way bank access on ds_read_b128 (free, m136).
__global__ __launch_bounds__(256) void gemm_kernel(
    const unsigned short* __restrict__ fhi, const unsigned short* __restrict__ flo,
    const unsigned short* __restrict__ whi, const unsigned short* __restrict__ wlo,
    const int* __restrict__ targets, const float* __restrict__ ctm,
    const float* __restrict__ flt, const float* __restrict__ tnew,
    float* __restrict__ out) {
    __shared__ unsigned short lds[4][128][32]; // Ahi, Alo, Bhi, Blo : 32 KB

    const int t = threadIdx.x;
    const int w = t >> 6, l = t & 63;
    const int wr = w >> 1, wc = w & 1;
    const int fr = l & 15, kgrp = l >> 4;
    const int col0 = blockIdx.x * 128;
    const int row0 = blockIdx.y * 128;

    // --- staging setup: 8 sections per thread (section ss = w + 4*i) ---
    // Each wave-issue stages 16 rows x 64B. Lane l: row r0+(l>>2), 16B slot
    // (l&3)^((l>>3)&3) of the row's 64B k-chunk (pre-swizzled global source).
    const unsigned short* gsrc[8];
    unsigned short* ldst[8];
    {
        int rsec = l >> 2;
        int slot = (l & 3) ^ ((l >> 3) & 3);
#pragma unroll
        for (int i = 0; i < 8; i++) {
            int ss = w + 4 * i;
            int buf = ss >> 3;        // 0:Ahi 1:Alo 2:Bhi 3:Blo
            int r0 = (ss & 7) * 16;
            int r = r0 + rsec;
            const unsigned short* base;
            int grow;
            if (buf == 0) { base = fhi; grow = row0 + r; }
            else if (buf == 1) { base = flo; grow = row0 + r; }
            else {
                int c = col0 + r;
                if (c > C_SZ - 1) c = C_SZ - 1; // clamp: avoid OOB read past wlo
                base = (buf == 2) ? whi : wlo;
                grow = c;
            }
            gsrc[i] = base + (size_t)grow * D_SZ + slot * 8;
            ldst[i] = &lds[buf][r0][0]; // wave-uniform; HW adds lane*16
        }
    }

    // fragment read addresses: swizzle term depends only on fr bits 1-2
    const unsigned swz = ((unsigned)((fr >> 1) & 3)) << 4;
    const unsigned kb = ((unsigned)(kgrp * 16)) ^ swz;
    const char* aph = (const char*)&lds[0][0][0] + (unsigned)(wr * 64 + fr) * 64 + kb;
    const char* apl = (const char*)&lds[1][0][0] + (unsigned)(wr * 64 + fr) * 64 + kb;
    const char* bph = (const char*)&lds[2][0][0] + (unsigned)(wc * 64 + fr) * 64 + kb;
    const char* bpl = (const char*)&lds[3][0][0] + (unsigned)(wc * 64 + fr) * 64 + kb;

    f32x4 acc[4][4] = {};

    for (int kt = 0; kt < D_SZ; kt += 32) {
#pragma unroll
        for (int i = 0; i < 8; i++) {
            __builtin_amdgcn_global_load_lds((g_void*)(gsrc[i] + kt),
                                             (lds_void*)ldst[i], 16, 0, 0);
        }
        __syncthreads(); // compiler drains vmcnt(0) here (m97 structure)

        bf16x8 ah[4], al[4];
#pragma unroll
        for (int mi = 0; mi < 4; mi++) {
            ah[mi] = *(const bf16x8*)(aph + mi * 1024);
            al[mi] = *(const bf16x8*)(apl + mi * 1024);
        }
#pragma unroll
        for (int ni = 0; ni < 4; ni++) {
            bf16x8 bh = *(const bf16x8*)(bph + ni * 1024);
            bf16x8 bl = *(const bf16x8*)(bpl + ni * 1024);
#pragma unroll
            for (int mi = 0; mi < 4; mi++) {
                // per-acc order (hh, hl, lh) over ascending kt == rounds 3/4
                acc[mi][ni] = __builtin_amdgcn_mfma_f32_16x16x32_bf16(
                    ah[mi], bh, acc[mi][ni], 0, 0, 0);
                acc[mi][ni] = __builtin_amdgcn_mfma_f32_16x16x32_bf16(
                    ah[mi], bl, acc[mi][ni], 0, 0, 0);
                acc[mi][ni] = __builtin_amdgcn_mfma_f32_16x16x32_bf16(
                    al[mi], bh, acc[mi][ni], 0, 0, 0);
            }
        }
        __syncthreads();
    }

    // fused ArcFace epilogue; D frag: col = lane&15, row = (lane>>4)*4 + reg
    float tn = tnew[0];
#pragma unroll
    for (int mi = 0; mi < 4; mi++) {
#pragma unroll
        for (int j = 0; j < 4; j++) {
            int r = row0 + wr * 64 + mi * 16 + (l >> 4) * 4 + j;
            int tg = targets[r];
            float cm = ctm[r], fl = flt[r];
            size_t base = (size_t)r * C_SZ;
#pragma unroll
            for (int ni = 0; ni < 4; ni++) {
                int cg = col0 + wc * 64 + ni * 16;
                if (cg < C_SZ) { // C%16==0 -> all-or-nothing per 16-col group
                    int c = cg + fr;
                    float v = acc[mi][ni][j];
                    if (c == tg) v = fl;
                    else if (v > cm) v = v * (tn + v);
                    out[base + c] = v * S_SCALE;
                }
            }
        }
    }
}

// bulk copy weight -> out new_weight region (overwrites packed Whi/Wlo AFTER gemm)
__global__ __launch_bounds__(256) void copyw_kernel(
    const float4* __restrict__ src, float4* __restrict__ dst, int n4) {
    int i = blockIdx.x * blockDim.x + threadIdx.x;
    if (i < n4) dst[i] = src[i];
}

// per-unique-target EMA weight update; targets cached in LDS, parallel dedup.
__global__ __launch_bounds__(256) void updw_kernel(
    const int* __restrict__ targets, const float* __restrict__ f,
    const float* __restrict__ weight, float* __restrict__ outw) {
    __shared__ int tg[B_SZ];
    __shared__ int dup;
    int t = threadIdx.x;
    if (t == 0) dup = 0;
    tg[t] = targets[t];
    tg[t + 256] = targets[t + 256];
    __syncthreads();
    int b = blockIdx.x;
    int c = tg[b];
    if ((t < b && tg[t] == c) || (t + 256 < b && tg[t + 256] == c)) dup = 1;
    __syncthreads();
    if (dup) return; // uniform: not the first occurrence

    float sum = 0.f;
    int cnt = 0;
    for (int i = b; i < B_SZ; i++) {
        if (tg[i] == c) { sum += f[i * D_SZ + t]; cnt++; }
    }
    float mean = sum / (float)cnt;
    float upd = 0.5f * weight[(size_t)c * D_SZ + t] + 0.5f * mean;
    float v = wave_reduce_sum(upd * upd);
    __shared__ float red[4];
    int wave = t >> 6, lane = t & 63;
    if (lane == 0) red[wave] = v;
    __syncthreads();
    float s = red[0] + red[1] + red[2] + red[3];
    float nrm = fmaxf(sqrtf(s), EPSc);
    outw[(size_t)c * D_SZ + t] = upd / nrm;
}

extern "C" void kernel_launch(void* const* d_in, const int* in_sizes, int n_in,
                              void* d_out, int out_size, void* d_ws, size_t ws_size,
                              hipStream_t stream) {
    const float* features = (const float*)d_in[0];
    const int* targets = (const int*)d_in[1];
    const float* weight = (const float*)d_in[2];
    const float* t_in = (const float*)d_in[3];
    float* out = (float*)d_out;
    char* wsb = (char*)d_ws;

    float* f = (float*)(wsb + WSB_F);
    unsigned short* fhi = (unsigned short*)(wsb + WSB_FHI);
    unsigned short* flo = (unsigned short*)(wsb + WSB_FLO);
    float* tl = (float*)(wsb + WSB_TL);
    float* ctm = (float*)(wsb + WSB_CTM);
    float* flt = (float*)(wsb + WSB_FLT);
    float* tnew = (float*)(wsb + WSB_TNEW);

    // packed split-W lives in the out new_weight region until copyw/updw
    unsigned short* whi = (unsigned short*)(out + OUT_W_OFF);
    unsigned short* wlo = whi + (size_t)C_SZ * D_SZ;

    prep_kernel<<<B_SZ, 256, 0, stream>>>(features, targets, weight, f, fhi, flo,
                                          tl, ctm, flt);
    tnew_kernel<<<1, 512, 0, stream>>>(tl, t_in, tnew, out + OUT_T_OFF);

    wpack_kernel<<<12500, 256, 0, stream>>>(weight, whi, wlo);

    dim3 ggrid((C_SZ + 127) / 128, B_SZ / 128); // 782 x 4
    gemm_kernel<<<ggrid, 256, 0, stream>>>(fhi, flo, whi, wlo, targets, ctm, flt,
                                           tnew, out);

    int n4 = (C_SZ * D_SZ) / 4;
    copyw_kernel<<<(n4 + 255) / 256, 256, 0, stream>>>(
        (const float4*)weight, (float4*)(out + OUT_W_OFF), n4);

    updw_kernel<<<B_SZ, 256, 0, stream>>>(targets, f, weight, out + OUT_W_OFF);
}

// Round 7
// 515.420 us; speedup vs baseline: 1.4336x; 1.1295x over previous
//
#include <hip/hip_runtime.h>
#include <math.h>

// ---- problem constants (fixed by reference) ----
#define B_SZ 512
#define D_SZ 256
#define C_SZ 100000
#define S_SCALE 30.0f
#define COS_Mc 0.8775825618903728f        // cos(0.5)
#define SIN_Mc 0.479425538604203f         // sin(0.5)
#define THRESHOLDc (-0.8775825618903728f) // cos(pi-0.5)
#define MMc 0.2397127693021015f           // sin(pi-0.5)*0.5
#define EPSc 1e-12f

// d_out layout (floats): [logits B*C][new_weight C*D][t_new 1]
#define OUT_W_OFF ((size_t)B_SZ * C_SZ)             // 51,200,000
#define OUT_T_OFF (OUT_W_OFF + (size_t)C_SZ * D_SZ) // 76,800,000

// ws layout (bytes)
#define WSB_F 0              // f fp32 [512][256]
#define WSB_FHI 524288       // f_hi bf16 [512][256]
#define WSB_FLO 786432       // f_lo bf16 [512][256]
#define WSB_TL 1048576       // target_logit [512] f32
#define WSB_CTM 1050624      // cos_theta_m [512] f32
#define WSB_FLT 1052672      // final_target_logit [512] f32
#define WSB_TNEW 1054720     // t_new [1] f32

typedef __attribute__((ext_vector_type(8))) short bf16x8; // MFMA A/B frag
typedef __attribute__((ext_vector_type(4))) float f32x4;  // MFMA C/D frag
typedef __attribute__((address_space(3))) void lds_void;
typedef const __attribute__((address_space(1))) void g_void;

__device__ __forceinline__ float wave_reduce_sum(float v) {
#pragma unroll
    for (int off = 32; off > 0; off >>= 1) v += __shfl_down(v, off, 64);
    return v;
}

__device__ __forceinline__ unsigned short f2bf(float x) { // RNE fp32->bf16
    union { float f; unsigned u; } v; v.f = x;
    unsigned r = v.u + 0x7fff + ((v.u >> 16) & 1);
    return (unsigned short)(r >> 16);
}
__device__ __forceinline__ float bf2f(unsigned short h) {
    union { float f; unsigned u; } v;
    v.u = ((unsigned)h) << 16;
    return v.f;
}

// One block per batch row: normalize, emit f / f_hi / f_lo, target dot, margin scalars.
__global__ __launch_bounds__(256) void prep_kernel(
    const float* __restrict__ features, const int* __restrict__ targets,
    const float* __restrict__ weight, float* __restrict__ f,
    unsigned short* __restrict__ fhi, unsigned short* __restrict__ flo,
    float* __restrict__ tl, float* __restrict__ ctm, float* __restrict__ flt) {
    int b = blockIdx.x;
    int d = threadIdx.x;
    float x = features[b * D_SZ + d];
    float v = wave_reduce_sum(x * x);
    __shared__ float red[4];
    int wave = d >> 6, lane = d & 63;
    if (lane == 0) red[wave] = v;
    __syncthreads();
    float s = red[0] + red[1] + red[2] + red[3];
    float scale = 1.0f / fmaxf(sqrtf(s), EPSc);
    float fv = x * scale;
    f[b * D_SZ + d] = fv;
    unsigned short h = f2bf(fv);
    fhi[b * D_SZ + d] = h;
    flo[b * D_SZ + d] = f2bf(fv - bf2f(h));

    int tgt = targets[b];
    float wv = weight[(size_t)tgt * D_SZ + d];
    float p = wave_reduce_sum(fv * wv);
    __syncthreads();
    if (lane == 0) red[wave] = p;
    __syncthreads();
    if (d == 0) {
        float t_l = red[0] + red[1] + red[2] + red[3];
        tl[b] = t_l;
        float sin_t = sqrtf(fmaxf(1.0f - t_l * t_l, 0.0f));
        float c_m = t_l * COS_Mc - sin_t * SIN_Mc;
        ctm[b] = c_m;
        flt[b] = (t_l > THRESHOLDc) ? c_m : (t_l - MMc);
    }
}

// One block: t_new = mean(tl)*0.01 + 0.99*t
__global__ __launch_bounds__(512) void tnew_kernel(
    const float* __restrict__ tl, const float* __restrict__ t_in,
    float* __restrict__ tnew_ws, float* __restrict__ out_t) {
    int i = threadIdx.x;
    float v = wave_reduce_sum(tl[i]);
    __shared__ float red[8];
    int wave = i >> 6, lane = i & 63;
    if (lane == 0) red[wave] = v;
    __syncthreads();
    if (i == 0) {
        float s = 0.f;
#pragma unroll
        for (int w = 0; w < 8; w++) s += red[w];
        float tn = (s / (float)B_SZ) * 0.01f + 0.99f * t_in[0];
        tnew_ws[0] = tn;
        out_t[0] = tn;
    }
}

// m97-style LDS-staged split-bf16 MFMA GEMM, W converted fp32->hi/lo IN-KERNEL.
// Block 128x128, BK=32, 4 waves 2x2 (wave tile 64x64 = 4x4 frags 16x16x32).
// A (fhi/flo) staged via global_load_lds(16B) with pre-swizzled source;
// W staged global->reg->convert->swizzled ds_write_b128 (reg-staging allows
// write-side swizzle). LDS layout: phys_byte(r,o) = r*64 + (o ^ (((r>>1)&3)<<4)).
__global__ __launch_bounds__(256) void gemm_kernel(
    const unsigned short* __restrict__ fhi, const unsigned short* __restrict__ flo,
    const float* __restrict__ weight,
    const int* __restrict__ targets, const float* __restrict__ ctm,
    const float* __restrict__ flt, const float* __restrict__ tnew,
    float* __restrict__ out) {
    __shared__ unsigned short lds[4][128][32]; // 0:Ahi 1:Alo 2:Bhi 3:Blo : 32 KB

    const int t = threadIdx.x;
    const int w = t >> 6, l = t & 63;
    const int wr = w >> 1, wc = w & 1;
    const int fr = l & 15, kgrp = l >> 4;
    const int col0 = blockIdx.x * 128;
    const int row0 = blockIdx.y * 128;

    // --- A staging setup: 16 sections (8 Ahi + 8 Alo), 4 issues/thread ---
    const unsigned short* gsrcA[4];
    unsigned short* ldstA[4];
    {
        int rsec = l >> 2;
        int slot = (l & 3) ^ ((l >> 3) & 3); // pre-swizzled global source
#pragma unroll
        for (int i = 0; i < 4; i++) {
            int ss = w + 4 * i;        // 0..15
            int buf = ss >> 3;         // 0:Ahi 1:Alo
            int r0 = (ss & 7) * 16;
            const unsigned short* base = buf ? flo : fhi;
            gsrcA[i] = base + (size_t)(row0 + r0 + rsec) * D_SZ + slot * 8;
            ldstA[i] = &lds[buf][r0][0]; // wave-uniform; HW adds lane*16
        }
    }

    // --- W reg-staging setup: thread t handles row t>>1, half t&1 (16 floats) ---
    const int wrow_l = t >> 1;             // 0..127
    const int wh = t & 1;
    int wrow_g = col0 + wrow_l;
    if (wrow_g > C_SZ - 1) wrow_g = C_SZ - 1; // clamp (epilogue masks)
    const float* wbase = weight + (size_t)wrow_g * D_SZ + wh * 16;
    // swizzled ds_write addresses
    const unsigned swzr = (((unsigned)wrow_l >> 1) & 3) << 4;
    const unsigned bo0 = ((unsigned)wh * 32) ^ swzr;
    const unsigned bo1 = ((unsigned)wh * 32 + 16) ^ swzr;
    char* bhi_w = (char*)&lds[2][0][0] + (unsigned)wrow_l * 64;
    char* blo_w = (char*)&lds[3][0][0] + (unsigned)wrow_l * 64;

    // fragment read addresses (identical to prior round's verified layout)
    const unsigned swz = ((unsigned)((fr >> 1) & 3)) << 4;
    const unsigned kb = ((unsigned)(kgrp * 16)) ^ swz;
    const char* aph = (const char*)&lds[0][0][0] + (unsigned)(wr * 64 + fr) * 64 + kb;
    const char* apl = (const char*)&lds[1][0][0] + (unsigned)(wr * 64 + fr) * 64 + kb;
    const char* bph = (const char*)&lds[2][0][0] + (unsigned)(wc * 64 + fr) * 64 + kb;
    const char* bpl = (const char*)&lds[3][0][0] + (unsigned)(wc * 64 + fr) * 64 + kb;

    f32x4 acc[4][4] = {};

    // prologue: W fp32 regs for kt=0
    float4 wv0 = *(const float4*)(wbase + 0);
    float4 wv1 = *(const float4*)(wbase + 4);
    float4 wv2 = *(const float4*)(wbase + 8);
    float4 wv3 = *(const float4*)(wbase + 12);

    for (int kt = 0; kt < D_SZ; kt += 32) {
        // convert current W regs -> 4x bf16x8 (overlaps prev-step MFMA tail)
        union { unsigned short us[8]; bf16x8 v; } h0, h1, l0, l1;
        {
            float xs[16] = {wv0.x, wv0.y, wv0.z, wv0.w, wv1.x, wv1.y, wv1.z, wv1.w,
                            wv2.x, wv2.y, wv2.z, wv2.w, wv3.x, wv3.y, wv3.z, wv3.w};
#pragma unroll
            for (int j = 0; j < 8; j++) {
                unsigned short hh = f2bf(xs[j]);
                h0.us[j] = hh; l0.us[j] = f2bf(xs[j] - bf2f(hh));
                unsigned short hh2 = f2bf(xs[j + 8]);
                h1.us[j] = hh2; l1.us[j] = f2bf(xs[j + 8] - bf2f(hh2));
            }
        }
        if (kt) __syncthreads(); // prior step's LDS reads complete
        // A: async global->LDS
#pragma unroll
        for (int i = 0; i < 4; i++)
            __builtin_amdgcn_global_load_lds((g_void*)(gsrcA[i] + kt),
                                             (lds_void*)ldstA[i], 16, 0, 0);
        // W: swizzled ds_write of converted tile
        *(bf16x8*)(bhi_w + bo0) = h0.v;
        *(bf16x8*)(bhi_w + bo1) = h1.v;
        *(bf16x8*)(blo_w + bo0) = l0.v;
        *(bf16x8*)(blo_w + bo1) = l1.v;
        __syncthreads(); // drains vmcnt (A) + lgkm (W writes)

        // issue next-step W loads now: latency hides under MFMAs
        if (kt + 32 < D_SZ) {
            wv0 = *(const float4*)(wbase + kt + 32);
            wv1 = *(const float4*)(wbase + kt + 36);
            wv2 = *(const float4*)(wbase + kt + 40);
            wv3 = *(const float4*)(wbase + kt + 44);
        }

        bf16x8 ah[4], al[4];
#pragma unroll
        for (int mi = 0; mi < 4; mi++) {
            ah[mi] = *(const bf16x8*)(aph + mi * 1024);
            al[mi] = *(const bf16x8*)(apl + mi * 1024);
        }
#pragma unroll
        for (int ni = 0; ni < 4; ni++) {
            bf16x8 bh = *(const bf16x8*)(bph + ni * 1024);
            bf16x8 bl = *(const bf16x8*)(bpl + ni * 1024);
#pragma unroll
            for (int mi = 0; mi < 4; mi++) {
                // per-acc order (hh, hl, lh) over ascending kt == prior rounds
                acc[mi][ni] = __builtin_amdgcn_mfma_f32_16x16x32_bf16(
                    ah[mi], bh, acc[mi][ni], 0, 0, 0);
                acc[mi][ni] = __builtin_amdgcn_mfma_f32_16x16x32_bf16(
                    ah[mi], bl, acc[mi][ni], 0, 0, 0);
                acc[mi][ni] = __builtin_amdgcn_mfma_f32_16x16x32_bf16(
                    al[mi], bh, acc[mi][ni], 0, 0, 0);
            }
        }
    }

    // fused ArcFace epilogue; D frag: col = lane&15, row = (lane>>4)*4 + reg
    float tn = tnew[0];
#pragma unroll
    for (int mi = 0; mi < 4; mi++) {
#pragma unroll
        for (int j = 0; j < 4; j++) {
            int r = row0 + wr * 64 + mi * 16 + (l >> 4) * 4 + j;
            int tg = targets[r];
            float cm = ctm[r], fl = flt[r];
            size_t base = (size_t)r * C_SZ;
#pragma unroll
            for (int ni = 0; ni < 4; ni++) {
                int cg = col0 + wc * 64 + ni * 16;
                if (cg < C_SZ) { // C%16==0 -> all-or-nothing per 16-col group
                    int c = cg + fr;
                    float v = acc[mi][ni][j];
                    if (c == tg) v = fl;
                    else if (v > cm) v = v * (tn + v);
                    out[base + c] = v * S_SCALE;
                }
            }
        }
    }
}

// bulk copy weight -> out new_weight region
__global__ __launch_bounds__(256) void copyw_kernel(
    const float4* __restrict__ src, float4* __restrict__ dst, int n4) {
    int i = blockIdx.x * blockDim.x + threadIdx.x;
    if (i < n4) dst[i] = src[i];
}

// per-unique-target EMA weight update; targets cached in LDS, parallel dedup.
__global__ __launch_bounds__(256) void updw_kernel(
    const int* __restrict__ targets, const float* __restrict__ f,
    const float* __restrict__ weight, float* __restrict__ outw) {
    __shared__ int tg[B_SZ];
    __shared__ int dup;
    int t = threadIdx.x;
    if (t == 0) dup = 0;
    tg[t] = targets[t];
    tg[t + 256] = targets[t + 256];
    __syncthreads();
    int b = blockIdx.x;
    int c = tg[b];
    if ((t < b && tg[t] == c) || (t + 256 < b && tg[t + 256] == c)) dup = 1;
    __syncthreads();
    if (dup) return; // uniform: not the first occurrence

    float sum = 0.f;
    int cnt = 0;
    for (int i = b; i < B_SZ; i++) {
        if (tg[i] == c) { sum += f[i * D_SZ + t]; cnt++; }
    }
    float mean = sum / (float)cnt;
    float upd = 0.5f * weight[(size_t)c * D_SZ + t] + 0.5f * mean;
    float v = wave_reduce_sum(upd * upd);
    __shared__ float red[4];
    int wave = t >> 6, lane = t & 63;
    if (lane == 0) red[wave] = v;
    __syncthreads();
    float s = red[0] + red[1] + red[2] + red[3];
    float nrm = fmaxf(sqrtf(s), EPSc);
    outw[(size_t)c * D_SZ + t] = upd / nrm;
}

extern "C" void kernel_launch(void* const* d_in, const int* in_sizes, int n_in,
                              void* d_out, int out_size, void* d_ws, size_t ws_size,
                              hipStream_t stream) {
    const float* features = (const float*)d_in[0];
    const int* targets = (const int*)d_in[1];
    const float* weight = (const float*)d_in[2];
    const float* t_in = (const float*)d_in[3];
    float* out = (float*)d_out;
    char* wsb = (char*)d_ws;

    float* f = (float*)(wsb + WSB_F);
    unsigned short* fhi = (unsigned short*)(wsb + WSB_FHI);
    unsigned short* flo = (unsigned short*)(wsb + WSB_FLO);
    float* tl = (float*)(wsb + WSB_TL);
    float* ctm = (float*)(wsb + WSB_CTM);
    float* flt = (float*)(wsb + WSB_FLT);
    float* tnew = (float*)(wsb + WSB_TNEW);

    prep_kernel<<<B_SZ, 256, 0, stream>>>(features, targets, weight, f, fhi, flo,
                                          tl, ctm, flt);
    tnew_kernel<<<1, 512, 0, stream>>>(tl, t_in, tnew, out + OUT_T_OFF);

    dim3 ggrid((C_SZ + 127) / 128, B_SZ / 128); // 782 x 4
    gemm_kernel<<<ggrid, 256, 0, stream>>>(fhi, flo, weight, targets, ctm, flt,
                                           tnew, out);

    int n4 = (C_SZ * D_SZ) / 4;
    copyw_kernel<<<(n4 + 255) / 256, 256, 0, stream>>>(
        (const float4*)weight, (float4*)(out + OUT_W_OFF), n4);

    updw_kernel<<<B_SZ, 256, 0, stream>>>(targets, f, weight, out + OUT_W_OFF);
}